// Round 8
// baseline (293.707 us; speedup 1.0000x reference)
//
#include <hip/hip_runtime.h>

#define TSEQ 2048
#define DMODEL 1024
#define NHEAD 16
#define HDIM 64
#define NB 2
#define MROWS 4096   // NB*TSEQ
#define NQKV 3072    // 3*DMODEL
#define QSCALE 0.1803368801111204f  // 0.125 * log2(e): folds softmax scale+log2 into Q
#define ROPE_C (13.2877123795494f / 32.0f)  // log2(10000)/32
#define NEGINF -3.0e38f

using s16x8 = __attribute__((ext_vector_type(8))) short;
using s16x4 = __attribute__((ext_vector_type(4))) short;
using f32x4 = __attribute__((ext_vector_type(4))) float;
using u32x2 = __attribute__((ext_vector_type(2))) unsigned int;

static __device__ __forceinline__ float b2f(unsigned short u) {
  union { unsigned int i; float f; } x; x.i = ((unsigned int)u) << 16; return x.f;
}
static __device__ __forceinline__ unsigned short f2b(float f) {
  unsigned int u = __float_as_uint(f);
  u += 0x7fffu + ((u >> 16) & 1u);   // round-to-nearest-even
  return (unsigned short)(u >> 16);
}

// async 16B global -> LDS. LDS dest = wave-uniform base + lane*16 (m104).
typedef const __attribute__((address_space(1))) char gchar;
typedef __attribute__((address_space(3))) char lchar;
static __device__ __forceinline__ void gload_lds16(const void* g, void* l) {
  __builtin_amdgcn_global_load_lds((gchar*)g, (lchar*)l, 16, 0, 0);
}

// ---------------- 1) merged prep: x->bf16 convert + both weight transposes ----
__global__ __launch_bounds__(256) void k_prep(const float* __restrict__ x,
                                              short* __restrict__ xb,
                                              const float* __restrict__ wq,
                                              short* __restrict__ wqT,
                                              const float* __restrict__ wo,
                                              short* __restrict__ woT) {
  __shared__ float tile[32][33];
  const int blk = blockIdx.x;
  const int tid = threadIdx.x;
  if (blk < 4096) {
    const int i = blk * 256 + tid;
    const float4 v = ((const float4*)x)[i];
    s16x4 o;
    o.x = (short)f2b(v.x); o.y = (short)f2b(v.y);
    o.z = (short)f2b(v.z); o.w = (short)f2b(v.w);
    ((s16x4*)xb)[i] = o;
    return;
  }
  const float* in; short* out; int C, bx, by;
  if (blk < 7168) {
    const int l = blk - 4096; in = wq; out = wqT; C = NQKV;
    bx = l % 96; by = l / 96;
  } else {
    const int l = blk - 7168; in = wo; out = woT; C = DMODEL;
    bx = l & 31; by = l >> 5;
  }
  const int tx = tid & 31, ty4 = (tid >> 5) * 4;
#pragma unroll
  for (int i = 0; i < 4; ++i)
    tile[ty4 + i][tx] = in[(by * 32 + ty4 + i) * C + bx * 32 + tx];
  __syncthreads();
#pragma unroll
  for (int i = 0; i < 4; ++i)
    out[(bx * 32 + ty4 + i) * DMODEL + by * 32 + tx] = (short)f2b(tile[tx][ty4 + i]);
}

// ---------------- 2) fused QKV GEMM (BK=64) + head rearrange -----------------
// C[4096][3072] = xb[4096][1024] * wqkvT[3072][1024]^T, 128x128 tiles, BK=64:
// half the barrier pairs of BK=32. LDS rows are 128B = 8 x 16B chunks,
// XOR-swizzled phys = g ^ (row&7). Epilogue: pure data movement.
__global__ __launch_bounds__(256) void k_gemm_qkv(const short* __restrict__ A,
                                                  const short* __restrict__ BT,
                                                  short* __restrict__ Qo,
                                                  short* __restrict__ Ko,
                                                  short* __restrict__ Vt) {
  __shared__ __attribute__((aligned(16))) short As[128 * 64];
  __shared__ __attribute__((aligned(16))) short Bs[128 * 64];
  const int K = DMODEL;
  const int tid = threadIdx.x;
  const int wave = tid >> 6, lane = tid & 63, quad = lane >> 4, l15 = lane & 15;
  const int wm = (wave >> 1) * 64, wn = (wave & 1) * 64;
  const int m0 = blockIdx.y * 128, n0 = blockIdx.x * 128;
  f32x4 acc[4][4] = {};
  const char* Ab = (const char*)A;
  const char* Bb = (const char*)BT;
  char* AsB = (char*)As;
  char* BsB = (char*)Bs;
  // staging: 1024 chunks of 16B per tile; thread handles 4 (pass p: idx p*256+tid)
  int srow[4], sg[4];
#pragma unroll
  for (int p = 0; p < 4; ++p) {
    const int i = p * 256 + tid;
    srow[p] = i >> 3;
    sg[p] = (i & 7) ^ (srow[p] & 7);
  }
  for (int k0 = 0; k0 < K; k0 += 64) {
    __syncthreads();
#pragma unroll
    for (int p = 0; p < 4; ++p) {
      const long go = ((long)(m0 + srow[p]) * K + k0) * 2 + sg[p] * 16;
      gload_lds16(Ab + go, AsB + p * 4096 + wave * 1024);
    }
#pragma unroll
    for (int p = 0; p < 4; ++p) {
      const long go = ((long)(n0 + srow[p]) * K + k0) * 2 + sg[p] * 16;
      gload_lds16(Bb + go, BsB + p * 4096 + wave * 1024);
    }
    __syncthreads();
#pragma unroll
    for (int hf = 0; hf < 2; ++hf) {
      s16x8 af[4], bf[4];
#pragma unroll
      for (int i = 0; i < 4; ++i) {
        const int ra = wm + i * 16 + l15;
        af[i] = *(const s16x8*)(AsB + ra * 128 + (((hf * 4 + quad) ^ (ra & 7)) * 16));
        const int rb = wn + i * 16 + l15;
        bf[i] = *(const s16x8*)(BsB + rb * 128 + (((hf * 4 + quad) ^ (rb & 7)) * 16));
      }
#pragma unroll
      for (int i = 0; i < 4; ++i)
#pragma unroll
        for (int j = 0; j < 4; ++j)
          acc[i][j] = __builtin_amdgcn_mfma_f32_16x16x32_bf16(af[i], bf[j], acc[i][j], 0, 0, 0);
    }
  }
  // ---- epilogue (data movement only) ----
  const int colbase = n0 + wn;              // multiple of 64
  const int region = colbase >> 10;         // 0=Q, 1=K, 2=V
  const int hh = (colbase & 1023) >> 6;
  const int bq = m0 >> 11;                  // batch (tile never straddles)
  const int tbase = (m0 & 2047) + wm;       // + i*16 + quad*4 (+ r)
  if (region == 2) {
    // V: direct transposed write, 8B packs (r = 4 consecutive t at fixed d)
    short* dst = Vt + (((long)(bq * NHEAD + hh) * HDIM) << 11);
#pragma unroll
    for (int i = 0; i < 4; ++i) {
      const int t0 = tbase + i * 16 + quad * 4;
#pragma unroll
      for (int j = 0; j < 4; ++j) {
        const int d = j * 16 + l15;
        s16x4 w;
        w.x = (short)f2b(acc[i][j][0]);
        w.y = (short)f2b(acc[i][j][1]);
        w.z = (short)f2b(acc[i][j][2]);
        w.w = (short)f2b(acc[i][j][3]);
        *(s16x4*)(dst + (((long)d) << 11) + t0) = w;
      }
    }
  } else {
    short* dst = (region ? Ko : Qo) + (long)(bq * NHEAD + hh) * TSEQ * HDIM;
#pragma unroll
    for (int i = 0; i < 4; ++i)
#pragma unroll
      for (int j = 0; j < 4; ++j) {
        const int d = j * 16 + l15;
#pragma unroll
        for (int r = 0; r < 4; ++r) {
          const int t = tbase + i * 16 + quad * 4 + r;
          dst[(long)t * HDIM + d] = (short)f2b(acc[i][j][r]);
        }
      }
  }
}

// ---------------- 3) rope K in place ([BH][T][64], coalesced 16B) ------------
__global__ __launch_bounds__(256) void k_ropek(short* __restrict__ Kp) {
  const int tt = blockIdx.x, bh = blockIdx.y;
  const int tid = threadIdx.x;
  const int row = tid >> 2, chunk = tid & 3;
  const int t = tt * 64 + row;
  short* base = Kp + ((long)bh * TSEQ + t) * HDIM + chunk * 8;
  const s16x8 lo = *(const s16x8*)base;
  const s16x8 hi = *(const s16x8*)(base + 32);
  s16x8 nlo, nhi;
  const float tf = (float)t;
#pragma unroll
  for (int j = 0; j < 8; ++j) {
    const float inv = exp2f(-(float)(chunk * 8 + j) * ROPE_C);
    float sn, cs;
    __sincosf(tf * inv, &sn, &cs);
    const float a = b2f((unsigned short)lo[j]);
    const float b = b2f((unsigned short)hi[j]);
    nlo[j] = (short)f2b(a * cs - b * sn);
    nhi[j] = (short)f2b(b * cs + a * sn);
  }
  *(s16x8*)base = nlo;
  *(s16x8*)(base + 32) = nhi;
}

// ---------------- 4) GEMM BMx128, BK=64: C = A[M][K] * BT[N][K]^T ------------
// IM=2 -> 64x128 tile (wave 32x64). Half the barriers of BK=32.
template <int IM, bool OUT_BF16>
__global__ __launch_bounds__(256) void k_gemm(const short* __restrict__ A,
                                              const short* __restrict__ BT,
                                              void* __restrict__ Cv,
                                              int M, int N, int K) {
  __shared__ __attribute__((aligned(16))) short As[IM * 32 * 64];
  __shared__ __attribute__((aligned(16))) short Bs[128 * 64];
  const int tid = threadIdx.x;
  const int wave = tid >> 6, lane = tid & 63, quad = lane >> 4, l15 = lane & 15;
  const int wm = (wave >> 1) * (IM * 16), wn = (wave & 1) * 64;
  const int m0 = blockIdx.y * (IM * 32), n0 = blockIdx.x * 128;
  f32x4 acc[IM][4] = {};
  const char* Ab = (const char*)A;
  const char* Bb = (const char*)BT;
  char* AsB = (char*)As;
  char* BsB = (char*)Bs;
  int srow[4], sg[4];
#pragma unroll
  for (int p = 0; p < 4; ++p) {
    const int i = p * 256 + tid;
    srow[p] = i >> 3;
    sg[p] = (i & 7) ^ (srow[p] & 7);
  }
  for (int k0 = 0; k0 < K; k0 += 64) {
    __syncthreads();
#pragma unroll
    for (int p = 0; p < IM; ++p) {
      const long go = ((long)(m0 + srow[p]) * K + k0) * 2 + sg[p] * 16;
      gload_lds16(Ab + go, AsB + p * 4096 + wave * 1024);
    }
#pragma unroll
    for (int p = 0; p < 4; ++p) {
      const long go = ((long)(n0 + srow[p]) * K + k0) * 2 + sg[p] * 16;
      gload_lds16(Bb + go, BsB + p * 4096 + wave * 1024);
    }
    __syncthreads();
#pragma unroll
    for (int hf = 0; hf < 2; ++hf) {
      s16x8 af[IM], bf[4];
#pragma unroll
      for (int i = 0; i < IM; ++i) {
        const int ra = wm + i * 16 + l15;
        af[i] = *(const s16x8*)(AsB + ra * 128 + (((hf * 4 + quad) ^ (ra & 7)) * 16));
      }
#pragma unroll
      for (int j = 0; j < 4; ++j) {
        const int rb = wn + j * 16 + l15;
        bf[j] = *(const s16x8*)(BsB + rb * 128 + (((hf * 4 + quad) ^ (rb & 7)) * 16));
      }
#pragma unroll
      for (int i = 0; i < IM; ++i)
#pragma unroll
        for (int j = 0; j < 4; ++j)
          acc[i][j] = __builtin_amdgcn_mfma_f32_16x16x32_bf16(af[i], bf[j], acc[i][j], 0, 0, 0);
    }
  }
#pragma unroll
  for (int i = 0; i < IM; ++i) {
    const int row = m0 + wm + i * 16 + quad * 4;
#pragma unroll
    for (int j = 0; j < 4; ++j) {
      const int col = n0 + wn + j * 16 + l15;
#pragma unroll
      for (int r = 0; r < 4; ++r) {
        if (OUT_BF16) ((short*)Cv)[(long)(row + r) * N + col] = (short)f2b(acc[i][j][r]);
        else          ((float*)Cv)[(long)(row + r) * N + col] = acc[i][j][r];
      }
    }
  }
}

// ---------------- 5) flash attention, ZERO-BARRIER (direct-global K/V) -------
// S^T = K Q^T in log2-units (Q roped+scaled at frag load). K frags register-
// prefetched one iter ahead (coalesced b128 global loads, issued right after
// current K's last use); V frags loaded at iter top (~300cyc before PV use).
// No LDS staging, no __syncthreads: only wave-private P scratch (8KB/block).
__global__ __launch_bounds__(256) __attribute__((amdgpu_waves_per_eu(3)))
void k_attn(const short* __restrict__ Qg,
            const short* __restrict__ Kg,
            const short* __restrict__ Vg,
            short* __restrict__ O) {
  __shared__ __attribute__((aligned(16))) short pl[4][16 * 64];  // XOR-swizzled [q][t]
  // CU balance: co-resident blocks get qi in {r, 15-r, 16+r, 31-r}.
  const int bx = blockIdx.x, by = blockIdx.y;
  const int r_ = (bx & 7) ^ (by & 7);
  const int idx_ = ((bx >> 3) + (by >> 3)) & 3;
  const int qi = (idx_ == 0) ? r_ : (idx_ == 1) ? 15 - r_ : (idx_ == 2) ? 16 + r_ : 31 - r_;
  const int bh = by;
  const int b = bh >> 4, h = bh & 15;
  const int tid = threadIdx.x, wave = tid >> 6, lane = tid & 63;
  const int quad = lane >> 4, l15 = lane & 15;
  const char* Kb = (const char*)(Kg + (long)bh * TSEQ * HDIM);
  const char* Vb = (const char*)(Vg + (long)bh * HDIM * TSEQ);
  const short* Qb = Qg + (long)bh * TSEQ * HDIM;
  const int qr0 = qi * 64 + wave * 16;
  // Q fragments (B operand: n=q on l15, k=d on quad*8+j) -- rope + QSCALE here
  const s16x8 rq0 = *(const s16x8*)&Qb[(qr0 + l15) * HDIM + quad * 8];
  const s16x8 rq1 = *(const s16x8*)&Qb[(qr0 + l15) * HDIM + 32 + quad * 8];
  s16x8 aq0, aq1;
  {
    const float tf = (float)(qr0 + l15);
#pragma unroll
    for (int j = 0; j < 8; ++j) {
      const float inv = exp2f(-(float)(quad * 8 + j) * ROPE_C);
      float sn, cs;
      __sincosf(tf * inv, &sn, &cs);
      sn *= QSCALE; cs *= QSCALE;
      const float q0 = b2f((unsigned short)rq0[j]);
      const float q1 = b2f((unsigned short)rq1[j]);
      aq0[j] = (short)f2b(q0 * cs - q1 * sn);
      aq1[j] = (short)f2b(q1 * cs + q0 * sn);
    }
  }
  f32x4 o[4] = {};          // O^T: d = hs*16 + quad*4 + r, q = l15
  float lsum = 0.0f;
  char* plwB = (char*)pl + wave * 2048;

  // lane-fixed base addresses for direct K/V fragment loads
  const char* kbase = Kb + l15 * 128 + quad * 16;   // + kj*8192 + j2*2048 (+64)
  const char* vbase = Vb + l15 * 4096 + quad * 16;  // + hs*65536 + kj*128 (+64)

  s16x8 kc[8];  // current K frags [j2*2+half]
#define KLD(kjv)                                                         \
  do {                                                                   \
    const char* kp_ = kbase + (kjv) * 8192;                              \
    _Pragma("unroll")                                                    \
    for (int j2 = 0; j2 < 4; ++j2) {                                     \
      kc[j2 * 2]     = *(const s16x8*)(kp_ + j2 * 2048);                 \
      kc[j2 * 2 + 1] = *(const s16x8*)(kp_ + j2 * 2048 + 64);            \
    }                                                                    \
  } while (0)
  KLD(0);

  for (int kj = 0; kj <= qi; ++kj) {
    // V loads for THIS iter (consumed ~300cyc later by PV)
    s16x8 vc[8];
    {
      const char* vp = vbase + kj * 128;
#pragma unroll
      for (int hs = 0; hs < 4; ++hs) {
        vc[hs * 2]     = *(const s16x8*)(vp + hs * 65536);
        vc[hs * 2 + 1] = *(const s16x8*)(vp + hs * 65536 + 64);
      }
    }
    // S^T = K Q^T using current K frags
    f32x4 s[4];
#pragma unroll
    for (int j2 = 0; j2 < 4; ++j2) {
      f32x4 z = {};
      z = __builtin_amdgcn_mfma_f32_16x16x32_bf16(kc[j2 * 2], aq0, z, 0, 0, 0);
      z = __builtin_amdgcn_mfma_f32_16x16x32_bf16(kc[j2 * 2 + 1], aq1, z, 0, 0, 0);
      s[j2] = z;
    }
    // prefetch next K tile (kc free after MFMA issue; lands by next iter)
    if (kj < qi) KLD(kj + 1);
    if (kj == qi) {  // causal: mask t_loc > q_loc (diagonal tile only)
      const int q_loc = wave * 16 + l15;
#pragma unroll
      for (int j2 = 0; j2 < 4; ++j2)
#pragma unroll
        for (int r = 0; r < 4; ++r)
          if (j2 * 16 + quad * 4 + r > q_loc) s[j2][r] = NEGINF;
    }
    // p = exp2(s) unnormalized; truncate to bf16; accumulate TRUNCATED values.
    float ps = 0.0f;
#pragma unroll
    for (int j2 = 0; j2 < 4; ++j2) {
      const unsigned int u0 = __float_as_uint(exp2f(s[j2][0])) & 0xffff0000u;
      const unsigned int u1 = __float_as_uint(exp2f(s[j2][1])) & 0xffff0000u;
      const unsigned int u2 = __float_as_uint(exp2f(s[j2][2])) & 0xffff0000u;
      const unsigned int u3 = __float_as_uint(exp2f(s[j2][3])) & 0xffff0000u;
      ps += __uint_as_float(u0) + __uint_as_float(u1) +
            __uint_as_float(u2) + __uint_as_float(u3);
      u32x2 w;
      w.x = (u0 >> 16) | u1;
      w.y = (u2 >> 16) | u3;
      const int t0 = j2 * 16 + quad * 4;
      *(u32x2*)(plwB + l15 * 128 + (((t0 >> 3) ^ (l15 & 7)) * 16) + (quad & 1) * 8) = w;
    }
    lsum += ps;
    // PV: O^T = V^T P^T. B-frag from wave-private LDS; A-frag = vc.
    const s16x8 bp0 = *(const s16x8*)(plwB + l15 * 128 + ((quad ^ (l15 & 7)) * 16));
    const s16x8 bp1 = *(const s16x8*)(plwB + l15 * 128 + (((4 + quad) ^ (l15 & 7)) * 16));
#pragma unroll
    for (int hs = 0; hs < 4; ++hs) {
      o[hs] = __builtin_amdgcn_mfma_f32_16x16x32_bf16(vc[hs * 2], bp0, o[hs], 0, 0, 0);
      o[hs] = __builtin_amdgcn_mfma_f32_16x16x32_bf16(vc[hs * 2 + 1], bp1, o[hs], 0, 0, 0);
    }
  }
#undef KLD
  lsum += __shfl_xor(lsum, 16);
  lsum += __shfl_xor(lsum, 32);
  const float rinv = 1.0f / lsum;
  const int t = qi * 64 + wave * 16 + l15;
  short* Orow = O + (long)(b * TSEQ + t) * DMODEL + h * HDIM + quad * 4;
#pragma unroll
  for (int hs = 0; hs < 4; ++hs) {
    s16x4 w;
    w.x = (short)f2b(o[hs][0] * rinv);
    w.y = (short)f2b(o[hs][1] * rinv);
    w.z = (short)f2b(o[hs][2] * rinv);
    w.w = (short)f2b(o[hs][3] * rinv);
    *(s16x4*)(Orow + hs * 16) = w;  // 8B store, d consecutive
  }
}

// ---------------- launch ----------------
extern "C" void kernel_launch(void* const* d_in, const int* in_sizes, int n_in,
                              void* d_out, int out_size, void* d_ws, size_t ws_size,
                              hipStream_t stream) {
  const float* x = (const float*)d_in[0];      // [2,2048,1024]
  const float* w_qkv = (const float*)d_in[1];  // [1024,3072]
  const float* w_out = (const float*)d_in[2];  // [1024,1024]
  float* out = (float*)d_out;                  // [2,2048,1024]
  char* ws = (char*)d_ws;

  short* xb    = (short*)(ws);                        //  8 MiB
  short* wqkvT = (short*)(ws + (8ll << 20));          //  6 MiB
  short* woutT = (short*)(ws + (14ll << 20));         //  2 MiB
  short* Qb    = (short*)(ws + (16ll << 20));         //  8 MiB
  short* Kb    = (short*)(ws + (24ll << 20));         //  8 MiB
  short* Vt    = (short*)(ws + (32ll << 20));         //  8 MiB
  short* Ob    = (short*)(ws + (40ll << 20));         //  8 MiB  (total 48 MiB)

  k_prep<<<dim3(8192), dim3(256), 0, stream>>>(x, xb, w_qkv, wqkvT, w_out, woutT);
  k_gemm_qkv<<<dim3(NQKV / 128, MROWS / 128), dim3(256), 0, stream>>>(
      xb, wqkvT, Qb, Kb, Vt);
  k_ropek<<<dim3(TSEQ / 64, NB * NHEAD), dim3(256), 0, stream>>>(Kb);
  k_attn<<<dim3(TSEQ / 64, NB * NHEAD), dim3(256), 0, stream>>>(Qb, Kb, Vt, Ob);
  k_gemm<2, false><<<dim3(DMODEL / 128, MROWS / 64), dim3(256), 0, stream>>>(
      Ob, woutT, (void*)out, MROWS, DMODEL, DMODEL);
}

// Round 9
// 192.520 us; speedup vs baseline: 1.5256x; 1.5256x over previous
//
#include <hip/hip_runtime.h>

#define TSEQ 2048
#define DMODEL 1024
#define NHEAD 16
#define HDIM 64
#define NB 2
#define MROWS 4096   // NB*TSEQ
#define NQKV 3072    // 3*DMODEL
#define QSCALE 0.1803368801111204f  // 0.125 * log2(e): folds softmax scale+log2 into Q
#define ROPE_C (13.2877123795494f / 32.0f)  // log2(10000)/32
#define NEGINF -3.0e38f

using s16x8 = __attribute__((ext_vector_type(8))) short;
using s16x4 = __attribute__((ext_vector_type(4))) short;
using f32x4 = __attribute__((ext_vector_type(4))) float;
using u32x2 = __attribute__((ext_vector_type(2))) unsigned int;

static __device__ __forceinline__ float b2f(unsigned short u) {
  union { unsigned int i; float f; } x; x.i = ((unsigned int)u) << 16; return x.f;
}
static __device__ __forceinline__ unsigned short f2b(float f) {
  unsigned int u = __float_as_uint(f);
  u += 0x7fffu + ((u >> 16) & 1u);   // round-to-nearest-even
  return (unsigned short)(u >> 16);
}

// async 16B global -> LDS. LDS dest = wave-uniform base + lane*16 (m104).
typedef const __attribute__((address_space(1))) char gchar;
typedef __attribute__((address_space(3))) char lchar;
static __device__ __forceinline__ void gload_lds16(const void* g, void* l) {
  __builtin_amdgcn_global_load_lds((gchar*)g, (lchar*)l, 16, 0, 0);
}

// ---------------- 1) merged prep: x->bf16 convert + both weight transposes ----
__global__ __launch_bounds__(256) void k_prep(const float* __restrict__ x,
                                              short* __restrict__ xb,
                                              const float* __restrict__ wq,
                                              short* __restrict__ wqT,
                                              const float* __restrict__ wo,
                                              short* __restrict__ woT) {
  __shared__ float tile[32][33];
  const int blk = blockIdx.x;
  const int tid = threadIdx.x;
  if (blk < 4096) {
    const int i = blk * 256 + tid;
    const float4 v = ((const float4*)x)[i];
    s16x4 o;
    o.x = (short)f2b(v.x); o.y = (short)f2b(v.y);
    o.z = (short)f2b(v.z); o.w = (short)f2b(v.w);
    ((s16x4*)xb)[i] = o;
    return;
  }
  const float* in; short* out; int C, bx, by;
  if (blk < 7168) {
    const int l = blk - 4096; in = wq; out = wqT; C = NQKV;
    bx = l % 96; by = l / 96;
  } else {
    const int l = blk - 7168; in = wo; out = woT; C = DMODEL;
    bx = l & 31; by = l >> 5;
  }
  const int tx = tid & 31, ty4 = (tid >> 5) * 4;
#pragma unroll
  for (int i = 0; i < 4; ++i)
    tile[ty4 + i][tx] = in[(by * 32 + ty4 + i) * C + bx * 32 + tx];
  __syncthreads();
#pragma unroll
  for (int i = 0; i < 4; ++i)
    out[(bx * 32 + ty4 + i) * DMODEL + by * 32 + tx] = (short)f2b(tile[tx][ty4 + i]);
}

// ---------------- 2) fused QKV GEMM (BK=64) + head rearrange -----------------
__global__ __launch_bounds__(256) void k_gemm_qkv(const short* __restrict__ A,
                                                  const short* __restrict__ BT,
                                                  short* __restrict__ Qo,
                                                  short* __restrict__ Ko,
                                                  short* __restrict__ Vt) {
  __shared__ __attribute__((aligned(16))) short As[128 * 64];
  __shared__ __attribute__((aligned(16))) short Bs[128 * 64];
  const int K = DMODEL;
  const int tid = threadIdx.x;
  const int wave = tid >> 6, lane = tid & 63, quad = lane >> 4, l15 = lane & 15;
  const int wm = (wave >> 1) * 64, wn = (wave & 1) * 64;
  const int m0 = blockIdx.y * 128, n0 = blockIdx.x * 128;
  f32x4 acc[4][4] = {};
  const char* Ab = (const char*)A;
  const char* Bb = (const char*)BT;
  char* AsB = (char*)As;
  char* BsB = (char*)Bs;
  int srow[4], sg[4];
#pragma unroll
  for (int p = 0; p < 4; ++p) {
    const int i = p * 256 + tid;
    srow[p] = i >> 3;
    sg[p] = (i & 7) ^ (srow[p] & 7);
  }
  for (int k0 = 0; k0 < K; k0 += 64) {
    __syncthreads();
#pragma unroll
    for (int p = 0; p < 4; ++p) {
      const long go = ((long)(m0 + srow[p]) * K + k0) * 2 + sg[p] * 16;
      gload_lds16(Ab + go, AsB + p * 4096 + wave * 1024);
    }
#pragma unroll
    for (int p = 0; p < 4; ++p) {
      const long go = ((long)(n0 + srow[p]) * K + k0) * 2 + sg[p] * 16;
      gload_lds16(Bb + go, BsB + p * 4096 + wave * 1024);
    }
    __syncthreads();
#pragma unroll
    for (int hf = 0; hf < 2; ++hf) {
      s16x8 af[4], bf[4];
#pragma unroll
      for (int i = 0; i < 4; ++i) {
        const int ra = wm + i * 16 + l15;
        af[i] = *(const s16x8*)(AsB + ra * 128 + (((hf * 4 + quad) ^ (ra & 7)) * 16));
        const int rb = wn + i * 16 + l15;
        bf[i] = *(const s16x8*)(BsB + rb * 128 + (((hf * 4 + quad) ^ (rb & 7)) * 16));
      }
#pragma unroll
      for (int i = 0; i < 4; ++i)
#pragma unroll
        for (int j = 0; j < 4; ++j)
          acc[i][j] = __builtin_amdgcn_mfma_f32_16x16x32_bf16(af[i], bf[j], acc[i][j], 0, 0, 0);
    }
  }
  // ---- epilogue (data movement only) ----
  const int colbase = n0 + wn;              // multiple of 64
  const int region = colbase >> 10;         // 0=Q, 1=K, 2=V
  const int hh = (colbase & 1023) >> 6;
  const int bq = m0 >> 11;                  // batch (tile never straddles)
  const int tbase = (m0 & 2047) + wm;       // + i*16 + quad*4 (+ r)
  if (region == 2) {
    short* dst = Vt + (((long)(bq * NHEAD + hh) * HDIM) << 11);
#pragma unroll
    for (int i = 0; i < 4; ++i) {
      const int t0 = tbase + i * 16 + quad * 4;
#pragma unroll
      for (int j = 0; j < 4; ++j) {
        const int d = j * 16 + l15;
        s16x4 w;
        w.x = (short)f2b(acc[i][j][0]);
        w.y = (short)f2b(acc[i][j][1]);
        w.z = (short)f2b(acc[i][j][2]);
        w.w = (short)f2b(acc[i][j][3]);
        *(s16x4*)(dst + (((long)d) << 11) + t0) = w;
      }
    }
  } else {
    short* dst = (region ? Ko : Qo) + (long)(bq * NHEAD + hh) * TSEQ * HDIM;
#pragma unroll
    for (int i = 0; i < 4; ++i)
#pragma unroll
      for (int j = 0; j < 4; ++j) {
        const int d = j * 16 + l15;
#pragma unroll
        for (int r = 0; r < 4; ++r) {
          const int t = tbase + i * 16 + quad * 4 + r;
          dst[(long)t * HDIM + d] = (short)f2b(acc[i][j][r]);
        }
      }
  }
}

// ---------------- 3) rope K in place ([BH][T][64], coalesced 16B) ------------
__global__ __launch_bounds__(256) void k_ropek(short* __restrict__ Kp) {
  const int tt = blockIdx.x, bh = blockIdx.y;
  const int tid = threadIdx.x;
  const int row = tid >> 2, chunk = tid & 3;
  const int t = tt * 64 + row;
  short* base = Kp + ((long)bh * TSEQ + t) * HDIM + chunk * 8;
  const s16x8 lo = *(const s16x8*)base;
  const s16x8 hi = *(const s16x8*)(base + 32);
  s16x8 nlo, nhi;
  const float tf = (float)t;
#pragma unroll
  for (int j = 0; j < 8; ++j) {
    const float inv = exp2f(-(float)(chunk * 8 + j) * ROPE_C);
    float sn, cs;
    __sincosf(tf * inv, &sn, &cs);
    const float a = b2f((unsigned short)lo[j]);
    const float b = b2f((unsigned short)hi[j]);
    nlo[j] = (short)f2b(a * cs - b * sn);
    nhi[j] = (short)f2b(b * cs + a * sn);
  }
  *(s16x8*)base = nlo;
  *(s16x8*)(base + 32) = nhi;
}

// ---------------- 4) GEMM BMx128, BK=64: C = A[M][K] * BT[N][K]^T ------------
template <int IM, bool OUT_BF16>
__global__ __launch_bounds__(256) void k_gemm(const short* __restrict__ A,
                                              const short* __restrict__ BT,
                                              void* __restrict__ Cv,
                                              int M, int N, int K) {
  __shared__ __attribute__((aligned(16))) short As[IM * 32 * 64];
  __shared__ __attribute__((aligned(16))) short Bs[128 * 64];
  const int tid = threadIdx.x;
  const int wave = tid >> 6, lane = tid & 63, quad = lane >> 4, l15 = lane & 15;
  const int wm = (wave >> 1) * (IM * 16), wn = (wave & 1) * 64;
  const int m0 = blockIdx.y * (IM * 32), n0 = blockIdx.x * 128;
  f32x4 acc[IM][4] = {};
  const char* Ab = (const char*)A;
  const char* Bb = (const char*)BT;
  char* AsB = (char*)As;
  char* BsB = (char*)Bs;
  int srow[4], sg[4];
#pragma unroll
  for (int p = 0; p < 4; ++p) {
    const int i = p * 256 + tid;
    srow[p] = i >> 3;
    sg[p] = (i & 7) ^ (srow[p] & 7);
  }
  for (int k0 = 0; k0 < K; k0 += 64) {
    __syncthreads();
#pragma unroll
    for (int p = 0; p < IM; ++p) {
      const long go = ((long)(m0 + srow[p]) * K + k0) * 2 + sg[p] * 16;
      gload_lds16(Ab + go, AsB + p * 4096 + wave * 1024);
    }
#pragma unroll
    for (int p = 0; p < 4; ++p) {
      const long go = ((long)(n0 + srow[p]) * K + k0) * 2 + sg[p] * 16;
      gload_lds16(Bb + go, BsB + p * 4096 + wave * 1024);
    }
    __syncthreads();
#pragma unroll
    for (int hf = 0; hf < 2; ++hf) {
      s16x8 af[IM], bf[4];
#pragma unroll
      for (int i = 0; i < IM; ++i) {
        const int ra = wm + i * 16 + l15;
        af[i] = *(const s16x8*)(AsB + ra * 128 + (((hf * 4 + quad) ^ (ra & 7)) * 16));
      }
#pragma unroll
      for (int j = 0; j < 4; ++j) {
        const int rb = wn + j * 16 + l15;
        bf[j] = *(const s16x8*)(BsB + rb * 128 + (((hf * 4 + quad) ^ (rb & 7)) * 16));
      }
#pragma unroll
      for (int i = 0; i < IM; ++i)
#pragma unroll
        for (int j = 0; j < 4; ++j)
          acc[i][j] = __builtin_amdgcn_mfma_f32_16x16x32_bf16(af[i], bf[j], acc[i][j], 0, 0, 0);
    }
  }
#pragma unroll
  for (int i = 0; i < IM; ++i) {
    const int row = m0 + wm + i * 16 + quad * 4;
#pragma unroll
    for (int j = 0; j < 4; ++j) {
      const int col = n0 + wn + j * 16 + l15;
#pragma unroll
      for (int r = 0; r < 4; ++r) {
        if (OUT_BF16) ((short*)Cv)[(long)(row + r) * N + col] = (short)f2b(acc[i][j][r]);
        else          ((float*)Cv)[(long)(row + r) * N + col] = acc[i][j][r];
      }
    }
  }
}

// ---------------- 5) flash attention, BQ=128, 8 waves, LDS-dbuf K/V ----------
// Transposed S^T = K Q^T, static softmax (log2-units), rope-Q at frag load.
// 512 threads stage each 64x64 K/V tile ONCE per 128 q-rows (half the staging
// of the BQ=64 version). Each wave owns 16 q-rows; waves above the diagonal
// skip compute (barriers uniform). LDS: 2*8K K + 2*8K V + 8*2K P = 48KB.
__global__ __launch_bounds__(512) __attribute__((amdgpu_waves_per_eu(4)))
void k_attn(const short* __restrict__ Qg,
            const short* __restrict__ Kg,
            const short* __restrict__ Vg,
            short* __restrict__ O) {
  __shared__ __attribute__((aligned(16))) short Ks[2][64 * 64];
  __shared__ __attribute__((aligned(16))) short Vs[2][64 * 64];
  __shared__ __attribute__((aligned(16))) short pl[8][16 * 64];  // XOR-swizzled [q][t]
  // CU balance: with gridDim.x=16, co-resident blocks are (bx,by),(bx,by+16);
  // qi = bit4(by) ? 15-bx : bx gives them r and 15-r (36 iters/CU constant).
  const int bx = blockIdx.x, by = blockIdx.y;
  const int qi = ((by >> 4) & 1) ? (15 - bx) : bx;
  const int bh = by;
  const int b = bh >> 4, h = bh & 15;
  const int tid = threadIdx.x, wave = tid >> 6, lane = tid & 63;
  const int quad = lane >> 4, l15 = lane & 15;
  const char* Kb = (const char*)(Kg + (long)bh * TSEQ * HDIM);
  const char* Vb = (const char*)(Vg + (long)bh * HDIM * TSEQ);
  const short* Qb = Qg + (long)bh * TSEQ * HDIM;
  const int qr0 = qi * 128 + wave * 16;
  // Q fragments (B operand: n=q on l15, k=d on quad*8+j) -- rope + QSCALE here
  const s16x8 rq0 = *(const s16x8*)&Qb[(qr0 + l15) * HDIM + quad * 8];
  const s16x8 rq1 = *(const s16x8*)&Qb[(qr0 + l15) * HDIM + 32 + quad * 8];
  s16x8 aq0, aq1;
  {
    const float tf = (float)(qr0 + l15);
#pragma unroll
    for (int j = 0; j < 8; ++j) {
      const float inv = exp2f(-(float)(quad * 8 + j) * ROPE_C);
      float sn, cs;
      __sincosf(tf * inv, &sn, &cs);
      sn *= QSCALE; cs *= QSCALE;
      const float q0 = b2f((unsigned short)rq0[j]);
      const float q1 = b2f((unsigned short)rq1[j]);
      aq0[j] = (short)f2b(q0 * cs - q1 * sn);
      aq1[j] = (short)f2b(q1 * cs + q0 * sn);
    }
  }
  f32x4 o[4] = {};          // O^T: d = hs*16 + quad*4 + r, q = l15
  float lsum = 0.0f;
  // staging: 512 chunks of 16B per tile, one per thread
  const int kr0 = tid >> 3, kg0 = (tid & 7) ^ (kr0 & 7);
  char* KsB = (char*)Ks;
  char* VsB = (char*)Vs;
  char* plwB = (char*)pl + wave * 2048;
  const int ldsw = wave * 1024;  // + lane*16 by HW

#define STAGE(kjv, buf)                                                     \
  do {                                                                      \
    gload_lds16(Kb + (kjv) * 8192 + (kr0 * 8 + kg0) * 16,                   \
                KsB + (buf) * 8192 + ldsw);                                 \
    gload_lds16(Vb + (kjv) * 128 + kr0 * (TSEQ * 2) + kg0 * 16,             \
                VsB + (buf) * 8192 + ldsw);                                 \
  } while (0)

  STAGE(0, 0);
  __syncthreads();  // vmcnt drained before barrier -> buf0 ready

  const int kjmax = 2 * qi + 1;      // last K-tile this block needs
  const int kjd = qr0 >> 6;          // this wave's diagonal tile (skip beyond)
  for (int kj = 0; kj <= kjmax; ++kj) {
    const int cur = kj & 1;
    if (kj < kjmax) STAGE(kj + 1, cur ^ 1);
    if (kj <= kjd) {
      const char* kb = KsB + cur * 8192;
      const char* vb = VsB + cur * 8192;
      // S^T = K Q^T: A = K-frag (m=t_loc on l15, k=d), B = Q-frag.
      f32x4 s[4];
#pragma unroll
      for (int j2 = 0; j2 < 4; ++j2) {
        const int row = j2 * 16 + l15;
        const s16x8 k0 = *(const s16x8*)(kb + row * 128 + ((quad ^ (row & 7)) * 16));
        const s16x8 k1 = *(const s16x8*)(kb + row * 128 + (((4 + quad) ^ (row & 7)) * 16));
        f32x4 z = {};
        z = __builtin_amdgcn_mfma_f32_16x16x32_bf16(k0, aq0, z, 0, 0, 0);
        z = __builtin_amdgcn_mfma_f32_16x16x32_bf16(k1, aq1, z, 0, 0, 0);
        s[j2] = z;
      }
      if (kj == kjd) {  // causal mask on this wave's diagonal tile
        const int qloc = (qr0 & 63) + l15;
#pragma unroll
        for (int j2 = 0; j2 < 4; ++j2)
#pragma unroll
          for (int r = 0; r < 4; ++r)
            if (j2 * 16 + quad * 4 + r > qloc) s[j2][r] = NEGINF;
      }
      // p = exp2(s) unnormalized; truncate to bf16; accumulate TRUNCATED.
      float ps = 0.0f;
#pragma unroll
      for (int j2 = 0; j2 < 4; ++j2) {
        const unsigned int u0 = __float_as_uint(exp2f(s[j2][0])) & 0xffff0000u;
        const unsigned int u1 = __float_as_uint(exp2f(s[j2][1])) & 0xffff0000u;
        const unsigned int u2 = __float_as_uint(exp2f(s[j2][2])) & 0xffff0000u;
        const unsigned int u3 = __float_as_uint(exp2f(s[j2][3])) & 0xffff0000u;
        ps += __uint_as_float(u0) + __uint_as_float(u1) +
              __uint_as_float(u2) + __uint_as_float(u3);
        u32x2 w;
        w.x = (u0 >> 16) | u1;
        w.y = (u2 >> 16) | u3;
        const int t0 = j2 * 16 + quad * 4;
        *(u32x2*)(plwB + l15 * 128 + (((t0 >> 3) ^ (l15 & 7)) * 16) + (quad & 1) * 8) = w;
      }
      lsum += ps;
      // PV: O^T = V^T P^T. B-frag from wave-private LDS; A-frag = staged V.
      const s16x8 bp0 = *(const s16x8*)(plwB + l15 * 128 + ((quad ^ (l15 & 7)) * 16));
      const s16x8 bp1 = *(const s16x8*)(plwB + l15 * 128 + (((4 + quad) ^ (l15 & 7)) * 16));
#pragma unroll
      for (int hs = 0; hs < 4; ++hs) {
        const int d = hs * 16 + l15;
        const s16x8 av0 = *(const s16x8*)(vb + d * 128 + ((quad ^ (d & 7)) * 16));
        const s16x8 av1 = *(const s16x8*)(vb + d * 128 + (((4 + quad) ^ (d & 7)) * 16));
        o[hs] = __builtin_amdgcn_mfma_f32_16x16x32_bf16(av0, bp0, o[hs], 0, 0, 0);
        o[hs] = __builtin_amdgcn_mfma_f32_16x16x32_bf16(av1, bp1, o[hs], 0, 0, 0);
      }
    }
    __syncthreads();  // uniform barrier: prefetch landed during compute
  }
#undef STAGE
  lsum += __shfl_xor(lsum, 16);
  lsum += __shfl_xor(lsum, 32);
  const float rinv = 1.0f / lsum;
  const int t = qr0 + l15;
  short* Orow = O + (long)(b * TSEQ + t) * DMODEL + h * HDIM + quad * 4;
#pragma unroll
  for (int hs = 0; hs < 4; ++hs) {
    s16x4 w;
    w.x = (short)f2b(o[hs][0] * rinv);
    w.y = (short)f2b(o[hs][1] * rinv);
    w.z = (short)f2b(o[hs][2] * rinv);
    w.w = (short)f2b(o[hs][3] * rinv);
    *(s16x4*)(Orow + hs * 16) = w;  // 8B store, d consecutive
  }
}

// ---------------- launch ----------------
extern "C" void kernel_launch(void* const* d_in, const int* in_sizes, int n_in,
                              void* d_out, int out_size, void* d_ws, size_t ws_size,
                              hipStream_t stream) {
  const float* x = (const float*)d_in[0];      // [2,2048,1024]
  const float* w_qkv = (const float*)d_in[1];  // [1024,3072]
  const float* w_out = (const float*)d_in[2];  // [1024,1024]
  float* out = (float*)d_out;                  // [2,2048,1024]
  char* ws = (char*)d_ws;

  short* xb    = (short*)(ws);                        //  8 MiB
  short* wqkvT = (short*)(ws + (8ll << 20));          //  6 MiB
  short* woutT = (short*)(ws + (14ll << 20));         //  2 MiB
  short* Qb    = (short*)(ws + (16ll << 20));         //  8 MiB
  short* Kb    = (short*)(ws + (24ll << 20));         //  8 MiB
  short* Vt    = (short*)(ws + (32ll << 20));         //  8 MiB
  short* Ob    = (short*)(ws + (40ll << 20));         //  8 MiB  (total 48 MiB)

  k_prep<<<dim3(8192), dim3(256), 0, stream>>>(x, xb, w_qkv, wqkvT, w_out, woutT);
  k_gemm_qkv<<<dim3(NQKV / 128, MROWS / 128), dim3(256), 0, stream>>>(
      xb, wqkvT, Qb, Kb, Vt);
  k_ropek<<<dim3(TSEQ / 64, NB * NHEAD), dim3(256), 0, stream>>>(Kb);
  k_attn<<<dim3(TSEQ / 128, NB * NHEAD), dim3(512), 0, stream>>>(Qb, Kb, Vt, Ob);
  k_gemm<2, false><<<dim3(DMODEL / 128, MROWS / 64), dim3(256), 0, stream>>>(
      Ob, woutT, (void*)out, MROWS, DMODEL, DMODEL);
}